// Round 1
// baseline (417.957 us; speedup 1.0000x reference)
//
#include <hip/hip_runtime.h>

// GAT dense attention, fp32 VALU implementation.
// Shapes (hardcoded from reference): B=4, N=2048, F_in=128, H=4, d=32.
// out[b][n][h*32+d] fp32, out_size = 4*2048*128.

#define LOG2E 1.4426950408889634f
constexpr int Bb = 4, Nn = 2048, Fin = 128, Hh = 4, Dd = 32;

// ---------------- Kernel 1: Wh = x @ W, s = Wh.a1, t = Wh.a2 ----------------
// grid 512 blocks x 64 threads; block -> (bh, 64-row tile); lane = row.
// W rows are read at wave-uniform addresses -> expect s_load (SGPR) reuse.
__global__ __launch_bounds__(64) void k1_wh(
    const float* __restrict__ x, const float* __restrict__ W,
    const float* __restrict__ a, float* __restrict__ Wh,
    float* __restrict__ sArr, float* __restrict__ tArr) {
  int blk = blockIdx.x;
  int bh = blk >> 5;          // 16 bh pairs, 32 tiles each
  int tile = blk & 31;
  int lane = threadIdx.x;
  int b = bh >> 2, h = bh & 3;
  int n = tile * 64 + lane;

  const float* xrow = x + (b * Nn + n) * Fin;
  const float* Wq = W + h * Fin * Dd;

  float acc[Dd];
#pragma unroll
  for (int d = 0; d < Dd; ++d) acc[d] = 0.f;

  for (int i = 0; i < Fin; i += 4) {
    float4 xv = *(const float4*)(xrow + i);
#pragma unroll
    for (int c = 0; c < 4; ++c) {
      float xs = (c == 0) ? xv.x : (c == 1) ? xv.y : (c == 2) ? xv.z : xv.w;
      const float* wr = Wq + (i + c) * Dd;   // wave-uniform address
#pragma unroll
      for (int d = 0; d < Dd; ++d) acc[d] += xs * wr[d];
    }
  }

  const float* ah = a + h * 2 * Dd;          // wave-uniform
  float s = 0.f, t = 0.f;
#pragma unroll
  for (int d = 0; d < Dd; ++d) {
    s += acc[d] * ah[d];
    t += acc[d] * ah[Dd + d];
  }

  float* whrow = Wh + (bh * Nn + n) * Dd;
#pragma unroll
  for (int d = 0; d < Dd; d += 4)
    *(float4*)(whrow + d) = make_float4(acc[d], acc[d + 1], acc[d + 2], acc[d + 3]);
  sArr[bh * Nn + n] = s;
  tArr[bh * Nn + n] = t;
}

// ------------- Kernel 2: T = max_j t; A,C per row; U,V per col --------------
// p_ij = exp2(max(A_i + U_j, C_i + V_j)) with
//   m = lrelu(s + T),  A = L*(s-m), C = L*(0.2s-m), U = L*t, V = 0.2L*t
__global__ __launch_bounds__(256) void k2_prep(
    const float* __restrict__ sArr, const float* __restrict__ tArr,
    float* __restrict__ A, float* __restrict__ C,
    float* __restrict__ U, float* __restrict__ V) {
  __shared__ float sm[256];
  int bh = blockIdx.x, tid = threadIdx.x;
  const float* tb = tArr + bh * Nn;
  float mx = -1e30f;
  for (int n = tid; n < Nn; n += 256) mx = fmaxf(mx, tb[n]);
  sm[tid] = mx;
  __syncthreads();
  for (int s = 128; s > 0; s >>= 1) {
    if (tid < s) sm[tid] = fmaxf(sm[tid], sm[tid + s]);
    __syncthreads();
  }
  float T = sm[0];
  for (int n = tid; n < Nn; n += 256) {
    float s = sArr[bh * Nn + n], t = tb[n];
    float e = s + T;
    float m = fmaxf(e, 0.2f * e);            // lrelu(s+T) = max_j lrelu(e_ij)
    A[bh * Nn + n] = LOG2E * (s - m);
    C[bh * Nn + n] = LOG2E * (0.2f * s - m);
    U[bh * Nn + n] = LOG2E * t;
    V[bh * Nn + n] = LOG2E * 0.2f * t;
  }
}

// ---------------- Kernel 3: h = softmax(e) @ Wh, elu, store -----------------
// grid 512 blocks x 256 threads. block -> (bh, 64-row tile).
// wave w handles j in [512w, 512w+512); lane = row. Partial num/den per wave,
// combined through LDS. Wh rows + U/V read wave-uniformly -> expect s_load.
__global__ __launch_bounds__(256) void k3_attn(
    const float* __restrict__ Wh, const float* __restrict__ A_,
    const float* __restrict__ C_, const float* __restrict__ U_,
    const float* __restrict__ V_, float* __restrict__ out) {
  __shared__ float red[64][3][Dd + 1];       // waves 1..3 partials
  int blk = blockIdx.x;
  int bh = blk >> 5;
  int tile = blk & 31;
  int w = threadIdx.x >> 6, lane = threadIdx.x & 63;
  int row = tile * 64 + lane;
  int b = bh >> 2, h = bh & 3;

  float Ar = A_[bh * Nn + row];
  float Cr = C_[bh * Nn + row];
  const float* whb = Wh + bh * Nn * Dd;
  const float* Ub = U_ + bh * Nn;
  const float* Vb = V_ + bh * Nn;

  float num[Dd];
  float den = 0.f;
#pragma unroll
  for (int d = 0; d < Dd; ++d) num[d] = 0.f;

  int j0 = w * 512, j1 = j0 + 512;
  for (int j = j0; j < j1; ++j) {
    float u = Ub[j];                         // wave-uniform
    float v = Vb[j];                         // wave-uniform
    float p = __builtin_amdgcn_exp2f(fmaxf(Ar + u, Cr + v));
    den += p;
    const float* wr = whb + j * Dd;          // wave-uniform row of Wh
#pragma unroll
    for (int d = 0; d < Dd; ++d) num[d] += p * wr[d];
  }

  if (w > 0) {
#pragma unroll
    for (int d = 0; d < Dd; ++d) red[lane][w - 1][d] = num[d];
    red[lane][w - 1][Dd] = den;
  }
  __syncthreads();
  if (w == 0) {
#pragma unroll
    for (int ww = 0; ww < 3; ++ww) {
#pragma unroll
      for (int d = 0; d < Dd; ++d) num[d] += red[lane][ww][d];
      den += red[lane][ww][Dd];
    }
    float rd = 1.0f / den;                   // den >= 1 by construction
    float* orow = out + (b * Nn + row) * (Hh * Dd) + h * Dd;
#pragma unroll
    for (int d = 0; d < Dd; ++d) {
      float hv = num[d] * rd;
      num[d] = hv > 0.f ? hv : (__builtin_amdgcn_exp2f(hv * LOG2E) - 1.0f);
    }
#pragma unroll
    for (int d = 0; d < Dd; d += 4)
      *(float4*)(orow + d) = make_float4(num[d], num[d + 1], num[d + 2], num[d + 3]);
  }
}

extern "C" void kernel_launch(void* const* d_in, const int* in_sizes, int n_in,
                              void* d_out, int out_size, void* d_ws, size_t ws_size,
                              hipStream_t stream) {
  const float* x = (const float*)d_in[0];   // (4,2048,128)
  const float* W = (const float*)d_in[1];   // (4,128,32)
  const float* a = (const float*)d_in[2];   // (4,64)
  float* out = (float*)d_out;               // (4,2048,128)

  float* wsf = (float*)d_ws;
  const int BHN = Bb * Hh * Nn;             // 32768
  float* Wh = wsf;                          // 16*2048*32 = 1048576
  float* sArr = Wh + 16 * Nn * Dd;
  float* tArr = sArr + BHN;
  float* A = tArr + BHN;
  float* C = A + BHN;
  float* U = C + BHN;
  float* V = U + BHN;

  k1_wh<<<dim3(512), dim3(64), 0, stream>>>(x, W, a, Wh, sArr, tArr);
  k2_prep<<<dim3(16), dim3(256), 0, stream>>>(sArr, tArr, A, C, U, V);
  k3_attn<<<dim3(512), dim3(256), 0, stream>>>(Wh, A, C, U, V, out);
}

// Round 2
// 161.532 us; speedup vs baseline: 2.5875x; 2.5875x over previous
//
#include <hip/hip_runtime.h>

// GAT dense attention, fp32 VALU implementation, LDS-staged.
// Shapes (hardcoded from reference): B=4, N=2048, F_in=128, H=4, d=32.
// out[b][n][h*32+d] fp32, out_size = 4*2048*128.

#define LOG2E 1.4426950408889634f
constexpr int Bb = 4, Nn = 2048, Fin = 128, Hh = 4, Dd = 32;
constexpr int JT = 128;   // j-tile for k3 LDS staging

// ---------------- Kernel 1: Wh = x @ W, s = Wh.a1, t = Wh.a2 ----------------
// 512 blocks x 64 threads; block -> (bh, 64-row tile); lane = row.
// W[h] (128x32 = 16 KB) staged in LDS; inner reads are lane-broadcast.
__global__ __launch_bounds__(64) void k1_wh(
    const float* __restrict__ x, const float* __restrict__ W,
    const float* __restrict__ a, float* __restrict__ Wh,
    float* __restrict__ sArr, float* __restrict__ tArr) {
  __shared__ float Wlds[Fin][Dd];    // 16 KB
  int blk = blockIdx.x;
  int bh = blk >> 5;                 // 16 bh pairs, 32 tiles each
  int tile = blk & 31;
  int lane = threadIdx.x;
  int b = bh >> 2, h = bh & 3;
  int n = tile * 64 + lane;

  // cooperative load of W[h]: 4096 floats = 1024 float4, 16 per lane, coalesced
  {
    const float4* Wq4 = (const float4*)(W + h * Fin * Dd);
    float4* dst4 = (float4*)&Wlds[0][0];
#pragma unroll
    for (int r = 0; r < 16; ++r) dst4[lane + r * 64] = Wq4[lane + r * 64];
  }
  __syncthreads();

  const float* xrow = x + (b * Nn + n) * Fin;

  float acc[Dd];
#pragma unroll
  for (int d = 0; d < Dd; ++d) acc[d] = 0.f;

  for (int i = 0; i < Fin; i += 4) {
    float4 xv = *(const float4*)(xrow + i);
#pragma unroll
    for (int c = 0; c < 4; ++c) {
      float xs = (c == 0) ? xv.x : (c == 1) ? xv.y : (c == 2) ? xv.z : xv.w;
#pragma unroll
      for (int d = 0; d < Dd; ++d) acc[d] += xs * Wlds[i + c][d];  // LDS broadcast
    }
  }

  const float* ah = a + h * 2 * Dd;
  float s = 0.f, t = 0.f;
#pragma unroll
  for (int d = 0; d < Dd; ++d) {
    s += acc[d] * ah[d];
    t += acc[d] * ah[Dd + d];
  }

  float* whrow = Wh + (bh * Nn + n) * Dd;
#pragma unroll
  for (int d = 0; d < Dd; d += 4)
    *(float4*)(whrow + d) = make_float4(acc[d], acc[d + 1], acc[d + 2], acc[d + 3]);
  sArr[bh * Nn + n] = s;
  tArr[bh * Nn + n] = t;
}

// ------------- Kernel 2: T = max_j t; A,C per row; U,V per col --------------
// p_ij = exp2(max(A_i + U_j, C_i + V_j)) with
//   m = lrelu(s + T),  A = L*(s-m), C = L*(0.2s-m), U = L*t, V = 0.2L*t
__global__ __launch_bounds__(256) void k2_prep(
    const float* __restrict__ sArr, const float* __restrict__ tArr,
    float* __restrict__ A, float* __restrict__ C,
    float* __restrict__ U, float* __restrict__ V) {
  __shared__ float sm[256];
  int bh = blockIdx.x, tid = threadIdx.x;
  const float* tb = tArr + bh * Nn;
  float mx = -1e30f;
  for (int n = tid; n < Nn; n += 256) mx = fmaxf(mx, tb[n]);
  sm[tid] = mx;
  __syncthreads();
  for (int s = 128; s > 0; s >>= 1) {
    if (tid < s) sm[tid] = fmaxf(sm[tid], sm[tid + s]);
    __syncthreads();
  }
  float T = sm[0];
  for (int n = tid; n < Nn; n += 256) {
    float s = sArr[bh * Nn + n], t = tb[n];
    float e = s + T;
    float m = fmaxf(e, 0.2f * e);            // lrelu(s+T) = max_j lrelu(e_ij)
    A[bh * Nn + n] = LOG2E * (s - m);
    C[bh * Nn + n] = LOG2E * (0.2f * s - m);
    U[bh * Nn + n] = LOG2E * t;
    V[bh * Nn + n] = LOG2E * 0.2f * t;
  }
}

// ---------------- Kernel 3: h = softmax(e) @ Wh, elu, store -----------------
// 512 blocks x 256 threads. block -> (bh, 64-row tile); lane = row.
// Wh/U/V staged per j-tile in LDS; wave w handles quarter of each tile.
// Partial num/den per wave combined through LDS at the end.
__global__ __launch_bounds__(256) void k3_attn(
    const float* __restrict__ Wh, const float* __restrict__ A_,
    const float* __restrict__ C_, const float* __restrict__ U_,
    const float* __restrict__ V_, float* __restrict__ out) {
  __shared__ float tWh[JT][Dd];              // 16 KB
  __shared__ float tU[JT];
  __shared__ float tV[JT];
  __shared__ float red[64][3][Dd + 1];       // waves 1..3 partials (~25 KB)

  int blk = blockIdx.x;
  int bh = blk >> 5;
  int tile = blk & 31;
  int tid = threadIdx.x;
  int w = tid >> 6, lane = tid & 63;
  int row = tile * 64 + lane;
  int b = bh >> 2, h = bh & 3;

  float Ar = A_[bh * Nn + row];
  float Cr = C_[bh * Nn + row];
  const float* whb = Wh + bh * Nn * Dd;
  const float* Ub = U_ + bh * Nn;
  const float* Vb = V_ + bh * Nn;

  float num[Dd];
  float den = 0.f;
#pragma unroll
  for (int d = 0; d < Dd; ++d) num[d] = 0.f;

  for (int jt = 0; jt < Nn; jt += JT) {
    // cooperative tile load: JT*32 = 4096 floats = 1024 float4, 4/thread
    {
      const float4* src4 = (const float4*)(whb + jt * Dd);
      float4* dst4 = (float4*)&tWh[0][0];
#pragma unroll
      for (int r = 0; r < 4; ++r) dst4[tid + r * 256] = src4[tid + r * 256];
      if (tid < JT) tU[tid] = Ub[jt + tid];
      else tV[tid - JT] = Vb[jt + tid - JT];
    }
    __syncthreads();

    int jbase = w * (JT / 4);
#pragma unroll 2
    for (int jj = 0; jj < JT / 4; ++jj) {
      int j = jbase + jj;
      float u = tU[j];                       // LDS broadcast
      float v = tV[j];
      float p = __builtin_amdgcn_exp2f(fmaxf(Ar + u, Cr + v));
      den += p;
#pragma unroll
      for (int d = 0; d < Dd; ++d) num[d] += p * tWh[j][d];  // LDS broadcast
    }
    __syncthreads();
  }

  if (w > 0) {
#pragma unroll
    for (int d = 0; d < Dd; ++d) red[lane][w - 1][d] = num[d];
    red[lane][w - 1][Dd] = den;
  }
  __syncthreads();
  if (w == 0) {
#pragma unroll
    for (int ww = 0; ww < 3; ++ww) {
#pragma unroll
      for (int d = 0; d < Dd; ++d) num[d] += red[lane][ww][d];
      den += red[lane][ww][Dd];
    }
    float rd = 1.0f / den;                   // final den >= 1 by construction
    float* orow = out + (b * Nn + row) * (Hh * Dd) + h * Dd;
#pragma unroll
    for (int d = 0; d < Dd; ++d) {
      float hv = num[d] * rd;
      num[d] = hv > 0.f ? hv : (__builtin_amdgcn_exp2f(hv * LOG2E) - 1.0f);
    }
#pragma unroll
    for (int d = 0; d < Dd; d += 4)
      *(float4*)(orow + d) = make_float4(num[d], num[d + 1], num[d + 2], num[d + 3]);
  }
}

extern "C" void kernel_launch(void* const* d_in, const int* in_sizes, int n_in,
                              void* d_out, int out_size, void* d_ws, size_t ws_size,
                              hipStream_t stream) {
  const float* x = (const float*)d_in[0];   // (4,2048,128)
  const float* W = (const float*)d_in[1];   // (4,128,32)
  const float* a = (const float*)d_in[2];   // (4,64)
  float* out = (float*)d_out;               // (4,2048,128)

  float* wsf = (float*)d_ws;
  const int BHN = Bb * Hh * Nn;             // 32768
  float* Wh = wsf;                          // 16*2048*32 = 1048576 floats
  float* sArr = Wh + 16 * Nn * Dd;
  float* tArr = sArr + BHN;
  float* A = tArr + BHN;
  float* C = A + BHN;
  float* U = C + BHN;
  float* V = U + BHN;

  k1_wh<<<dim3(512), dim3(64), 0, stream>>>(x, W, a, Wh, sArr, tArr);
  k2_prep<<<dim3(16), dim3(256), 0, stream>>>(sArr, tArr, A, C, U, V);
  k3_attn<<<dim3(512), dim3(256), 0, stream>>>(Wh, A, C, U, V, out);
}

// Round 3
// 100.170 us; speedup vs baseline: 4.1725x; 1.6126x over previous
//
#include <hip/hip_runtime.h>

// GAT dense attention. fp32 p-side on VALU, PV matmul on bf16 MFMA with
// hi/lo split (error ~2^-18, fp32-equivalent).
// Shapes: B=4, N=2048, F_in=128, H=4, d=32. out[b][n][h*32+d] fp32.

#define LOG2E 1.4426950408889634f
constexpr int Nn = 2048, Fin = 128, Dd = 32;

typedef __attribute__((ext_vector_type(8))) short short8;
typedef __attribute__((ext_vector_type(4))) float f32x4;

union FragCvt { unsigned int u[4]; short8 s; };

// ---------------- Kernel 1: Wh = x @ W, s, t, and bf16 hi/lo WhT ------------
// 512 blocks (16 bh x 32 row-tiles) x 256 thr. Wave w = Fin slice [32w,32w+32).
// LDS reduction; wave 0 writes s,t and WhT[part][bh][d][j] bf16 (coalesced).
__global__ __launch_bounds__(256) void k1_wh(
    const float* __restrict__ x, const float* __restrict__ W,
    const float* __restrict__ a, unsigned short* __restrict__ whTh,
    unsigned short* __restrict__ whTl, float* __restrict__ sArr,
    float* __restrict__ tArr) {
  __shared__ float Wlds[Fin][Dd];       // 16 KB
  __shared__ float red[3][64][Dd + 1];  // 25.3 KB
  int blk = blockIdx.x;
  int bh = blk >> 5, tile = blk & 31;
  int b = bh >> 2, h = bh & 3;
  int tid = threadIdx.x, w = tid >> 6, lane = tid & 63;
  int row = tile * 64 + lane;

  {  // stage W[h]: 4096 f32 = 1024 float4, 4 per thread, coalesced
    const float4* src = (const float4*)(W + h * Fin * Dd);
    float4* dst = (float4*)&Wlds[0][0];
#pragma unroll
    for (int r = 0; r < 4; ++r) dst[tid + r * 256] = src[tid + r * 256];
  }
  __syncthreads();

  const float* xrow = x + (size_t)(b * Nn + row) * Fin + w * 32;
  float4 xv[8];
#pragma unroll
  for (int r = 0; r < 8; ++r) xv[r] = ((const float4*)xrow)[r];

  float acc[Dd];
#pragma unroll
  for (int d = 0; d < Dd; ++d) acc[d] = 0.f;
#pragma unroll
  for (int c8 = 0; c8 < 8; ++c8) {
    float xs[4] = {xv[c8].x, xv[c8].y, xv[c8].z, xv[c8].w};
#pragma unroll
    for (int cc = 0; cc < 4; ++cc) {
      const float* wr = &Wlds[w * 32 + c8 * 4 + cc][0];  // broadcast
#pragma unroll
      for (int d = 0; d < Dd; ++d) acc[d] += xs[cc] * wr[d];
    }
  }
  if (w > 0) {
#pragma unroll
    for (int d = 0; d < Dd; ++d) red[w - 1][lane][d] = acc[d];
  }
  __syncthreads();
  if (w == 0) {
#pragma unroll
    for (int ww = 0; ww < 3; ++ww)
#pragma unroll
      for (int d = 0; d < Dd; ++d) acc[d] += red[ww][lane][d];
    const float* ah = a + h * 2 * Dd;
    float s = 0.f, t = 0.f;
#pragma unroll
    for (int d = 0; d < Dd; ++d) { s += acc[d] * ah[d]; t += acc[d] * ah[Dd + d]; }
    sArr[bh * Nn + row] = s;
    tArr[bh * Nn + row] = t;
    // exact truncation split: hi = top16(wh), lo = bf16(wh - hi)
#pragma unroll
    for (int d = 0; d < Dd; ++d) {
      unsigned int ub = __float_as_uint(acc[d]);
      float lof = acc[d] - __uint_as_float(ub & 0xFFFF0000u);
      size_t o = (size_t)(bh * Dd + d) * Nn + row;   // lanes -> consecutive j
      whTh[o] = (unsigned short)(ub >> 16);
      whTl[o] = (unsigned short)(__float_as_uint(lof) >> 16);
    }
  }
}

// ------------- Kernel 2: T = max_j t; A,C per row; U,V per col --------------
__global__ __launch_bounds__(256) void k2_prep(
    const float* __restrict__ sArr, const float* __restrict__ tArr,
    float* __restrict__ A, float* __restrict__ C,
    float* __restrict__ U, float* __restrict__ V) {
  __shared__ float sm[256];
  int bh = blockIdx.x, tid = threadIdx.x;
  const float* tb = tArr + bh * Nn;
  float mx = -1e30f;
  for (int n = tid; n < Nn; n += 256) mx = fmaxf(mx, tb[n]);
  sm[tid] = mx;
  __syncthreads();
  for (int s = 128; s > 0; s >>= 1) {
    if (tid < s) sm[tid] = fmaxf(sm[tid], sm[tid + s]);
    __syncthreads();
  }
  float T = sm[0];
  for (int n = tid; n < Nn; n += 256) {
    float s = sArr[bh * Nn + n], t = tb[n];
    float e = s + T;
    float m = fmaxf(e, 0.2f * e);            // lrelu(s+T) = max_j lrelu(e_ij)
    A[bh * Nn + n] = LOG2E * (s - m);
    C[bh * Nn + n] = LOG2E * (0.2f * s - m);
    U[bh * Nn + n] = LOG2E * t;
    V[bh * Nn + n] = LOG2E * 0.2f * t;
  }
}

// ---------------- Kernel 3: h = softmax(e) @ Wh via MFMA --------------------
// 512 blocks (16 bh x 32 tiles of 64 rows) x 256 thr = 4 waves (j-quarters).
// Per wave: 4 M-tiles of 16x16x32 bf16, no barriers in K-loop.
// A-frag (P) built in registers: lane(q,m): rows t*16+m, j = jb+q*8+jj.
// B-frag (Wh^T bf16) from global: lane(q,n): 16B dwordx4, L2-resident.
__global__ __launch_bounds__(256) void k3_attn(
    const unsigned short* __restrict__ whTh, const unsigned short* __restrict__ whTl,
    const float* __restrict__ A_, const float* __restrict__ C_,
    const float* __restrict__ U_, const float* __restrict__ V_,
    float* __restrict__ out) {
  __shared__ float Ut[Nn], Vt[Nn];        // 16 KB, staged once
  __shared__ float redN[4][64][Dd + 1];   // 33.8 KB, epilogue only
  __shared__ float redD[4][64];           // 1 KB
  int blk = blockIdx.x;
  int bh = blk >> 5, tile = blk & 31;
  int b = bh >> 2, h = bh & 3;
  int tid = threadIdx.x, w = tid >> 6, lane = tid & 63;
  int q = lane >> 4, m = lane & 15;

  {  // stage U,V: 2048 f32 each, 2 float4 per thread each, coalesced
    const float4* us = (const float4*)(U_ + bh * Nn);
    const float4* vs = (const float4*)(V_ + bh * Nn);
    float4* ud = (float4*)Ut;
    float4* vd = (float4*)Vt;
    ud[tid] = us[tid]; ud[tid + 256] = us[tid + 256];
    vd[tid] = vs[tid]; vd[tid + 256] = vs[tid + 256];
  }
  __syncthreads();

  float Ar[4], Cr[4];
#pragma unroll
  for (int t = 0; t < 4; ++t) {
    int row = tile * 64 + t * 16 + m;
    Ar[t] = A_[bh * Nn + row];
    Cr[t] = C_[bh * Nn + row];
  }

  f32x4 acc[4][2];
#pragma unroll
  for (int t = 0; t < 4; ++t)
#pragma unroll
    for (int dh = 0; dh < 2; ++dh) acc[t][dh] = (f32x4){0.f, 0.f, 0.f, 0.f};
  float den[4] = {0.f, 0.f, 0.f, 0.f};

  const unsigned short* ph_b = whTh + (size_t)bh * Dd * Nn;
  const unsigned short* pl_b = whTl + (size_t)bh * Dd * Nn;

  int jq = w * 512;
  for (int s = 0; s < 16; ++s) {
    int jb = jq + s * 32;
    // B fragments: lane(q,n=m): WhT[dh*16+n][jb+q*8 .. +7], 16 B each
    short8 Bh[2], Bl[2];
#pragma unroll
    for (int dh = 0; dh < 2; ++dh) {
      size_t o = (size_t)(dh * 16 + m) * Nn + jb + q * 8;
      FragCvt fh, fl;
      *(uint4*)fh.u = *(const uint4*)(ph_b + o);
      *(uint4*)fl.u = *(const uint4*)(pl_b + o);
      Bh[dh] = fh.s;
      Bl[dh] = fl.s;
    }
    float uu[8], vv[8];
    *(float4*)&uu[0] = *(const float4*)&Ut[jb + q * 8];
    *(float4*)&uu[4] = *(const float4*)&Ut[jb + q * 8 + 4];
    *(float4*)&vv[0] = *(const float4*)&Vt[jb + q * 8];
    *(float4*)&vv[4] = *(const float4*)&Vt[jb + q * 8 + 4];

#pragma unroll
    for (int t = 0; t < 4; ++t) {
      FragCvt Ph, Pl;
      float ds = 0.f;
#pragma unroll
      for (int k = 0; k < 4; ++k) {
        float e1 = Ar[t] + uu[2 * k],     e2 = Cr[t] + vv[2 * k];
        float p0 = __builtin_amdgcn_exp2f(fmaxf(e1, e2));
        e1 = Ar[t] + uu[2 * k + 1];       e2 = Cr[t] + vv[2 * k + 1];
        float p1 = __builtin_amdgcn_exp2f(fmaxf(e1, e2));
        ds += p0 + p1;
        unsigned int b0 = __float_as_uint(p0), b1 = __float_as_uint(p1);
        Ph.u[k] = (b1 & 0xFFFF0000u) | (b0 >> 16);
        float l0 = p0 - __uint_as_float(b0 & 0xFFFF0000u);
        float l1 = p1 - __uint_as_float(b1 & 0xFFFF0000u);
        Pl.u[k] = (__float_as_uint(l1) & 0xFFFF0000u) | (__float_as_uint(l0) >> 16);
      }
      den[t] += ds;
#pragma unroll
      for (int dh = 0; dh < 2; ++dh) {
        acc[t][dh] = __builtin_amdgcn_mfma_f32_16x16x32_bf16(Ph.s, Bh[dh], acc[t][dh], 0, 0, 0);
        acc[t][dh] = __builtin_amdgcn_mfma_f32_16x16x32_bf16(Pl.s, Bh[dh], acc[t][dh], 0, 0, 0);
        acc[t][dh] = __builtin_amdgcn_mfma_f32_16x16x32_bf16(Ph.s, Bl[dh], acc[t][dh], 0, 0, 0);
      }
    }
  }

  // den: rows live in lanes m, m+16, m+32, m+48 -> butterfly over q
#pragma unroll
  for (int t = 0; t < 4; ++t) {
    den[t] += __shfl_xor(den[t], 16);
    den[t] += __shfl_xor(den[t], 32);
  }
  // dump partials (C-layout: row = t*16 + q*4 + r, col = dh*16 + m)
#pragma unroll
  for (int t = 0; t < 4; ++t) {
#pragma unroll
    for (int dh = 0; dh < 2; ++dh)
#pragma unroll
      for (int r = 0; r < 4; ++r)
        redN[w][t * 16 + q * 4 + r][dh * 16 + m] = acc[t][dh][r];
    if (q == 0) redD[w][t * 16 + m] = den[t];
  }
  __syncthreads();

  // final: thread -> (row = tid>>2, 8-d group), fully coalesced store
  {
    int rl = tid >> 2, dg = (tid & 3) * 8;
    float num[8];
#pragma unroll
    for (int i = 0; i < 8; ++i)
      num[i] = redN[0][rl][dg + i] + redN[1][rl][dg + i] +
               redN[2][rl][dg + i] + redN[3][rl][dg + i];
    float dt = redD[0][rl] + redD[1][rl] + redD[2][rl] + redD[3][rl];
    float rd = 1.0f / dt;                 // den >= 1 by construction
    float* orow = out + (size_t)(b * Nn + tile * 64 + rl) * (4 * Dd) + h * Dd + dg;
#pragma unroll
    for (int i = 0; i < 8; ++i) {
      float hv = num[i] * rd;
      num[i] = hv > 0.f ? hv : (__builtin_amdgcn_exp2f(hv * LOG2E) - 1.0f);
    }
    *(float4*)orow = make_float4(num[0], num[1], num[2], num[3]);
    *((float4*)orow + 1) = make_float4(num[4], num[5], num[6], num[7]);
  }
}

extern "C" void kernel_launch(void* const* d_in, const int* in_sizes, int n_in,
                              void* d_out, int out_size, void* d_ws, size_t ws_size,
                              hipStream_t stream) {
  const float* x = (const float*)d_in[0];   // (4,2048,128)
  const float* W = (const float*)d_in[1];   // (4,128,32)
  const float* a = (const float*)d_in[2];   // (4,64)
  float* out = (float*)d_out;               // (4,2048,128)

  float* wsf = (float*)d_ws;
  float* sArr = wsf;                        // 6 x 32768 f32
  float* tArr = sArr + 32768;
  float* A = tArr + 32768;
  float* C = A + 32768;
  float* U = C + 32768;
  float* V = U + 32768;
  unsigned short* whTh = (unsigned short*)(V + 32768);     // 2 MB
  unsigned short* whTl = whTh + (size_t)16 * Dd * Nn;      // 2 MB

  k1_wh<<<dim3(512), dim3(256), 0, stream>>>(x, W, a, whTh, whTl, sArr, tArr);
  k2_prep<<<dim3(16), dim3(256), 0, stream>>>(sArr, tArr, A, C, U, V);
  k3_attn<<<dim3(512), dim3(256), 0, stream>>>(whTh, whTl, A, C, U, V, out);
}

// Round 4
// 84.306 us; speedup vs baseline: 4.9576x; 1.1882x over previous
//
#include <hip/hip_runtime.h>

// GAT dense attention. MFMA everywhere (f16 with hi/lo split where fp32
// accuracy is needed). Shapes: B=4, N=2048, F_in=128, H=4, d=32.
// out[b][n][h*32+d] fp32.

#define LOG2E 1.4426950408889634f
constexpr int Nn = 2048, Fin = 128, Dd = 32;

typedef _Float16 half8 __attribute__((ext_vector_type(8)));
typedef _Float16 half4v __attribute__((ext_vector_type(4)));
typedef float f32x4 __attribute__((ext_vector_type(4)));

// ---------------- Kernel 1: Wh = x @ W (f16 hi/lo MFMA), s, t, whT ----------
// 512 blocks (16 bh x 32 tiles of 64 rows) x 256 thr; wave = one 16-row M-tile.
// A = x rows (global, coalesced), B = W[h] (gathered, L2-hot). 3-product split
// keeps Wh fp32-exact (dropped lo*lo term ~2^-22). Epilogue stores whT as f16
// [bh][d][j] (k3's B layout) and s,t via 16-lane shuffle reduction.
__global__ __launch_bounds__(256) void k1_wh(
    const float* __restrict__ x, const float* __restrict__ W,
    const float* __restrict__ a, _Float16* __restrict__ whT,
    float* __restrict__ sArr, float* __restrict__ tArr) {
  int blk = blockIdx.x;
  int bh = blk >> 5, tile = blk & 31;
  int b = bh >> 2, h = bh & 3;
  int tid = threadIdx.x, w = tid >> 6, lane = tid & 63;
  int q = lane >> 4, m = lane & 15;
  int rowbase = tile * 64 + w * 16;          // wave's rows: rowbase + (0..15)

  const float* Wq = W + h * Fin * Dd;
  const float* xb = x + (size_t)(b * Nn + rowbase + m) * Fin;  // A row = m

  f32x4 acc[2];                              // nt: d 0..15 / 16..31
  acc[0] = (f32x4){0.f, 0.f, 0.f, 0.f};
  acc[1] = (f32x4){0.f, 0.f, 0.f, 0.f};

#pragma unroll
  for (int kt = 0; kt < 4; ++kt) {
    float4 x0 = *(const float4*)(xb + kt * 32 + q * 8);
    float4 x1 = *(const float4*)(xb + kt * 32 + q * 8 + 4);
    float xv[8] = {x0.x, x0.y, x0.z, x0.w, x1.x, x1.y, x1.z, x1.w};
    half8 Ah, Al;
#pragma unroll
    for (int j = 0; j < 8; ++j) {
      _Float16 hi = (_Float16)xv[j];
      Ah[j] = hi;
      Al[j] = (_Float16)(xv[j] - (float)hi);
    }
#pragma unroll
    for (int nt = 0; nt < 2; ++nt) {
      half8 Bh, Bl;
#pragma unroll
      for (int j = 0; j < 8; ++j) {          // B[k=q*8+j][n=m], stride-Dd gather
        float wv = Wq[(kt * 32 + q * 8 + j) * Dd + nt * 16 + m];
        _Float16 hi = (_Float16)wv;
        Bh[j] = hi;
        Bl[j] = (_Float16)(wv - (float)hi);
      }
      acc[nt] = __builtin_amdgcn_mfma_f32_16x16x32_f16(Ah, Bh, acc[nt], 0, 0, 0);
      acc[nt] = __builtin_amdgcn_mfma_f32_16x16x32_f16(Al, Bh, acc[nt], 0, 0, 0);
      acc[nt] = __builtin_amdgcn_mfma_f32_16x16x32_f16(Ah, Bl, acc[nt], 0, 0, 0);
    }
  }

  // C layout: lane(q,m) holds rows j = rowbase + q*4 + r, col d = nt*16 + m.
  // whT[bh][d][j] f16 store: 4 consecutive j per lane -> 8B half4 store.
#pragma unroll
  for (int nt = 0; nt < 2; ++nt) {
    int d = nt * 16 + m;
    half4v h4;
#pragma unroll
    for (int r = 0; r < 4; ++r) h4[r] = (_Float16)acc[nt][r];
    *(half4v*)(whT + (size_t)(bh * Dd + d) * Nn + rowbase + q * 4) = h4;
  }

  // s,t: per lane partial over its column d, reduce across the 16 m-lanes.
  const float* ah = a + h * 2 * Dd;
  float a1m0 = ah[m], a1m1 = ah[16 + m];
  float a2m0 = ah[Dd + m], a2m1 = ah[Dd + 16 + m];
#pragma unroll
  for (int r = 0; r < 4; ++r) {
    float ps = acc[0][r] * a1m0 + acc[1][r] * a1m1;
    float pt = acc[0][r] * a2m0 + acc[1][r] * a2m1;
#pragma unroll
    for (int off = 1; off < 16; off <<= 1) {
      ps += __shfl_xor(ps, off);
      pt += __shfl_xor(pt, off);
    }
    if (m == 0) {
      sArr[bh * Nn + rowbase + q * 4 + r] = ps;
      tArr[bh * Nn + rowbase + q * 4 + r] = pt;
    }
  }
}

// ---------------- Kernel 3: h = softmax(e) @ Wh via f16 MFMA ----------------
// 512 blocks (16 bh x 32 tiles of 64 rows) x 256 thr = 4 waves (j-quarters).
// Prologue (absorbs old k2): stage t -> U/V in LDS, block-reduce T, build A/C.
// Main loop: no barriers; P built on VALU (exp2), single f16 MFMA per d-half.
// Epilogue LDS is unioned over U/V (dead after the loop).
__global__ __launch_bounds__(256) void k3_attn(
    const _Float16* __restrict__ whT, const float* __restrict__ sArr,
    const float* __restrict__ tArr, float* __restrict__ out) {
  __shared__ float smem[4 * 64 * 33 + 256];  // 34.8 KB union
  float* Ut = smem;                          // [2048] (prologue/main)
  float* Vt = smem + 2048;                   // [2048]
  float* red = smem + 4096;                  // [256]  block max scratch

  int blk = blockIdx.x;
  int bh = blk >> 5, tile = blk & 31;
  int b = bh >> 2, h = bh & 3;
  int tid = threadIdx.x, w = tid >> 6, lane = tid & 63;
  int q = lane >> 4, m = lane & 15;

  // ---- prologue: U/V + global max T + per-row A/C ----
  float mx = -1e30f;
  for (int i = tid; i < Nn; i += 256) {
    float t = tArr[bh * Nn + i];
    Ut[i] = LOG2E * t;
    Vt[i] = (0.2f * LOG2E) * t;
    mx = fmaxf(mx, t);
  }
  red[tid] = mx;
  __syncthreads();
  for (int ss = 128; ss > 0; ss >>= 1) {
    if (tid < ss) red[tid] = fmaxf(red[tid], red[tid + ss]);
    __syncthreads();
  }
  float T = red[0];

  float Ar[4], Cr[4];
#pragma unroll
  for (int t = 0; t < 4; ++t) {
    float s = sArr[bh * Nn + tile * 64 + t * 16 + m];
    float e = s + T;
    float mm = fmaxf(e, 0.2f * e);           // m_i = lrelu(s_i + T), exact
    Ar[t] = LOG2E * (s - mm);
    Cr[t] = LOG2E * (0.2f * s - mm);
  }

  f32x4 acc[4][2];
#pragma unroll
  for (int t = 0; t < 4; ++t) {
    acc[t][0] = (f32x4){0.f, 0.f, 0.f, 0.f};
    acc[t][1] = (f32x4){0.f, 0.f, 0.f, 0.f};
  }
  float den[4] = {0.f, 0.f, 0.f, 0.f};

  const _Float16* wb = whT + (size_t)bh * Dd * Nn;

  // ---- main loop: 16 steps of 32 j, no barriers ----
  for (int s = 0; s < 16; ++s) {
    int jb = w * 512 + s * 32;
    half8 B0 = *(const half8*)(wb + (size_t)m * Nn + jb + q * 8);
    half8 B1 = *(const half8*)(wb + (size_t)(16 + m) * Nn + jb + q * 8);
    float uu[8], vv[8];
    *(float4*)&uu[0] = *(const float4*)&Ut[jb + q * 8];
    *(float4*)&uu[4] = *(const float4*)&Ut[jb + q * 8 + 4];
    *(float4*)&vv[0] = *(const float4*)&Vt[jb + q * 8];
    *(float4*)&vv[4] = *(const float4*)&Vt[jb + q * 8 + 4];

#pragma unroll
    for (int t = 0; t < 4; ++t) {
      half8 P;
      float ds = 0.f;
#pragma unroll
      for (int k = 0; k < 8; ++k) {
        float p = __builtin_amdgcn_exp2f(fmaxf(Ar[t] + uu[k], Cr[t] + vv[k]));
        ds += p;
        P[k] = (_Float16)p;                  // p in (0,1], f16-safe
      }
      den[t] += ds;
      acc[t][0] = __builtin_amdgcn_mfma_f32_16x16x32_f16(P, B0, acc[t][0], 0, 0, 0);
      acc[t][1] = __builtin_amdgcn_mfma_f32_16x16x32_f16(P, B1, acc[t][1], 0, 0, 0);
    }
  }

  // ---- epilogue: cross-wave reduce + softmax divide + elu + store ----
#pragma unroll
  for (int t = 0; t < 4; ++t) {              // den rows live in 4 q-copies
    den[t] += __shfl_xor(den[t], 16);
    den[t] += __shfl_xor(den[t], 32);
  }
  __syncthreads();                           // U/V dead; reuse smem
  float* redN = smem;                        // [4][64][33]
  float* redD = smem + 4 * 64 * 33;          // [4][64]
#pragma unroll
  for (int t = 0; t < 4; ++t) {
#pragma unroll
    for (int dh = 0; dh < 2; ++dh)
#pragma unroll
      for (int r = 0; r < 4; ++r)
        redN[(w * 64 + t * 16 + q * 4 + r) * 33 + dh * 16 + m] = acc[t][dh][r];
    if (q == 0) redD[w * 64 + t * 16 + m] = den[t];
  }
  __syncthreads();
  {
    int rl = tid >> 2, dg = (tid & 3) * 8;
    float num[8];
#pragma unroll
    for (int i = 0; i < 8; ++i)
      num[i] = redN[(0 * 64 + rl) * 33 + dg + i] + redN[(1 * 64 + rl) * 33 + dg + i] +
               redN[(2 * 64 + rl) * 33 + dg + i] + redN[(3 * 64 + rl) * 33 + dg + i];
    float dt = redD[rl] + redD[64 + rl] + redD[128 + rl] + redD[192 + rl];
    float rd = 1.0f / dt;                    // den >= 1 by construction
    float* orow = out + (size_t)(b * Nn + tile * 64 + rl) * (4 * Dd) + h * Dd + dg;
#pragma unroll
    for (int i = 0; i < 8; ++i) {
      float hv = num[i] * rd;
      num[i] = hv > 0.f ? hv : (__builtin_amdgcn_exp2f(hv * LOG2E) - 1.0f);
    }
    *(float4*)orow = make_float4(num[0], num[1], num[2], num[3]);
    *((float4*)orow + 1) = make_float4(num[4], num[5], num[6], num[7]);
  }
}

extern "C" void kernel_launch(void* const* d_in, const int* in_sizes, int n_in,
                              void* d_out, int out_size, void* d_ws, size_t ws_size,
                              hipStream_t stream) {
  const float* x = (const float*)d_in[0];   // (4,2048,128)
  const float* W = (const float*)d_in[1];   // (4,128,32)
  const float* a = (const float*)d_in[2];   // (4,64)
  float* out = (float*)d_out;               // (4,2048,128)

  float* wsf = (float*)d_ws;
  float* sArr = wsf;                        // 32768 f32
  float* tArr = sArr + 32768;               // 32768 f32
  _Float16* whT = (_Float16*)(tArr + 32768);  // 16*32*2048 f16 = 2 MB

  k1_wh<<<dim3(512), dim3(256), 0, stream>>>(x, W, a, whT, sArr, tArr);
  k3_attn<<<dim3(512), dim3(256), 0, stream>>>(whT, sArr, tArr, out);
}

// Round 5
// 77.098 us; speedup vs baseline: 5.4211x; 1.0935x over previous
//
#include <hip/hip_runtime.h>

// GAT dense attention. MFMA everywhere; softmax numerator factorized rank-1:
//   p_ij = exp2(max(A_i+U_j, C_i+V_j)) = max(alpha_i*E_j, beta_i*F_j)
// with all four factors in (0,1] -> pure packed-f16 inner loop, no exp.
// Shapes: B=4, N=2048, F_in=128, H=4, d=32. out[b][n][h*32+d] fp32.

#define LOG2E 1.4426950408889634f
constexpr int Nn = 2048, Fin = 128, Dd = 32;

typedef _Float16 half8 __attribute__((ext_vector_type(8)));
typedef _Float16 half4v __attribute__((ext_vector_type(4)));
typedef _Float16 half2v __attribute__((ext_vector_type(2)));
typedef float f32x4 __attribute__((ext_vector_type(4)));

union H8 { half2v h2[4]; half8 h8; };

// ---------------- Kernel 1: Wh = x @ W (f16 hi/lo MFMA), s, t, whT ----------
// 512 blocks (16 bh x 32 tiles of 64 rows) x 256 thr; wave = one 16-row M-tile.
// 3-product split keeps Wh fp32-exact. Stores whT f16 [bh][d][j] + s,t.
__global__ __launch_bounds__(256) void k1_wh(
    const float* __restrict__ x, const float* __restrict__ W,
    const float* __restrict__ a, _Float16* __restrict__ whT,
    float* __restrict__ sArr, float* __restrict__ tArr) {
  int blk = blockIdx.x;
  int bh = blk >> 5, tile = blk & 31;
  int b = bh >> 2, h = bh & 3;
  int tid = threadIdx.x, w = tid >> 6, lane = tid & 63;
  int q = lane >> 4, m = lane & 15;
  int rowbase = tile * 64 + w * 16;

  const float* Wq = W + h * Fin * Dd;
  const float* xb = x + (size_t)(b * Nn + rowbase + m) * Fin;

  f32x4 acc[2];
  acc[0] = (f32x4){0.f, 0.f, 0.f, 0.f};
  acc[1] = (f32x4){0.f, 0.f, 0.f, 0.f};

#pragma unroll
  for (int kt = 0; kt < 4; ++kt) {
    float4 x0 = *(const float4*)(xb + kt * 32 + q * 8);
    float4 x1 = *(const float4*)(xb + kt * 32 + q * 8 + 4);
    float xv[8] = {x0.x, x0.y, x0.z, x0.w, x1.x, x1.y, x1.z, x1.w};
    half8 Ah, Al;
#pragma unroll
    for (int j = 0; j < 8; ++j) {
      _Float16 hi = (_Float16)xv[j];
      Ah[j] = hi;
      Al[j] = (_Float16)(xv[j] - (float)hi);
    }
#pragma unroll
    for (int nt = 0; nt < 2; ++nt) {
      half8 Bh, Bl;
#pragma unroll
      for (int j = 0; j < 8; ++j) {
        float wv = Wq[(kt * 32 + q * 8 + j) * Dd + nt * 16 + m];
        _Float16 hi = (_Float16)wv;
        Bh[j] = hi;
        Bl[j] = (_Float16)(wv - (float)hi);
      }
      acc[nt] = __builtin_amdgcn_mfma_f32_16x16x32_f16(Ah, Bh, acc[nt], 0, 0, 0);
      acc[nt] = __builtin_amdgcn_mfma_f32_16x16x32_f16(Al, Bh, acc[nt], 0, 0, 0);
      acc[nt] = __builtin_amdgcn_mfma_f32_16x16x32_f16(Ah, Bl, acc[nt], 0, 0, 0);
    }
  }

  // C layout: lane(q,m) -> rows rowbase+q*4+r, col d = nt*16+m.
#pragma unroll
  for (int nt = 0; nt < 2; ++nt) {
    int d = nt * 16 + m;
    half4v h4;
#pragma unroll
    for (int r = 0; r < 4; ++r) h4[r] = (_Float16)acc[nt][r];
    *(half4v*)(whT + (size_t)(bh * Dd + d) * Nn + rowbase + q * 4) = h4;
  }

  const float* ah = a + h * 2 * Dd;
  float a1m0 = ah[m], a1m1 = ah[16 + m];
  float a2m0 = ah[Dd + m], a2m1 = ah[Dd + 16 + m];
#pragma unroll
  for (int r = 0; r < 4; ++r) {
    float ps = acc[0][r] * a1m0 + acc[1][r] * a1m1;
    float pt = acc[0][r] * a2m0 + acc[1][r] * a2m1;
#pragma unroll
    for (int off = 1; off < 16; off <<= 1) {
      ps += __shfl_xor(ps, off);
      pt += __shfl_xor(pt, off);
    }
    if (m == 0) {
      sArr[bh * Nn + rowbase + q * 4 + r] = ps;
      tArr[bh * Nn + rowbase + q * 4 + r] = pt;
    }
  }
}

// ---------------- Kernel 3: h = softmax(e) @ Wh via f16 MFMA ----------------
// 512 blocks (16 bh x 32 tiles of 64 rows) x 256 thr = 4 waves (j-quarters).
// Prologue: T = max t (block-reduce), E/F f16 tables in LDS, alpha/beta per row.
// Main loop (no barriers, no exp): P_pair = pk_max(aa*E2, bb*F2); den via fdot2.
__global__ __launch_bounds__(256) void k3_attn(
    const _Float16* __restrict__ whT, const float* __restrict__ sArr,
    const float* __restrict__ tArr, float* __restrict__ out) {
  __shared__ float smem[4 * 64 * 33 + 256];  // 34.8 KB union
  _Float16* Ef = (_Float16*)smem;            // [2048] f16 (1024 f32 slots)
  _Float16* Ff = (_Float16*)(smem + 1024);   // [2048] f16
  float* red = smem + 2048;                  // [256] block-max scratch

  int blk = blockIdx.x;
  int bh = blk >> 5, tile = blk & 31;
  int b = bh >> 2, h = bh & 3;
  int tid = threadIdx.x, w = tid >> 6, lane = tid & 63;
  int q = lane >> 4, m = lane & 15;

  // ---- prologue: T, then E_j = 2^(L(t-T)), F_j = 2^(0.2L(t-T)) ----
  float tv[8];
  float mx = -1e30f;
#pragma unroll
  for (int k = 0; k < 8; ++k) {
    tv[k] = tArr[bh * Nn + tid + k * 256];
    mx = fmaxf(mx, tv[k]);
  }
  red[tid] = mx;
  __syncthreads();
  for (int ss = 128; ss > 0; ss >>= 1) {
    if (tid < ss) red[tid] = fmaxf(red[tid], red[tid + ss]);
    __syncthreads();
  }
  float T = red[0];
  __syncthreads();                           // red dead before Ef overwrite? (red
                                             // overlaps smem[2048..]; Ef/Ff use
                                             // smem[0..2047] -> disjoint, safe)
#pragma unroll
  for (int k = 0; k < 8; ++k) {
    float dt = tv[k] - T;                    // <= 0
    Ef[tid + k * 256] = (_Float16)__builtin_amdgcn_exp2f(LOG2E * dt);
    Ff[tid + k * 256] = (_Float16)__builtin_amdgcn_exp2f(0.2f * LOG2E * dt);
  }

  // per-row alpha/beta (replicated f16 pairs)
  half2v aa[4], bb[4];
#pragma unroll
  for (int t = 0; t < 4; ++t) {
    float es = sArr[bh * Nn + tile * 64 + t * 16 + m] + T;
    float al = __builtin_amdgcn_exp2f(0.8f * LOG2E * fminf(es, 0.f));
    float be = __builtin_amdgcn_exp2f(-0.8f * LOG2E * fmaxf(es, 0.f));
    _Float16 ah_ = (_Float16)al, bh_ = (_Float16)be;
    aa[t] = (half2v){ah_, ah_};
    bb[t] = (half2v){bh_, bh_};
  }
  __syncthreads();                           // E/F visible to all waves

  f32x4 acc[4][2];
#pragma unroll
  for (int t = 0; t < 4; ++t) {
    acc[t][0] = (f32x4){0.f, 0.f, 0.f, 0.f};
    acc[t][1] = (f32x4){0.f, 0.f, 0.f, 0.f};
  }
  float den[4] = {0.f, 0.f, 0.f, 0.f};
  const half2v ones = (half2v){(_Float16)1.f, (_Float16)1.f};

  const _Float16* wb = whT + (size_t)bh * Dd * Nn;

  // ---- main loop: 16 steps of 32 j, no barriers, no exp ----
  for (int s = 0; s < 16; ++s) {
    int jb = w * 512 + s * 32;
    half8 B0 = *(const half8*)(wb + (size_t)m * Nn + jb + q * 8);
    half8 B1 = *(const half8*)(wb + (size_t)(16 + m) * Nn + jb + q * 8);
    H8 E, F;
    E.h8 = *(const half8*)&Ef[jb + q * 8];   // LDS b128, quad-broadcast
    F.h8 = *(const half8*)&Ff[jb + q * 8];

#pragma unroll
    for (int t = 0; t < 4; ++t) {
      H8 P;
#pragma unroll
      for (int kk = 0; kk < 4; ++kk) {
        half2v pe = aa[t] * E.h2[kk];                        // v_pk_mul_f16
        half2v pf = bb[t] * F.h2[kk];                        // v_pk_mul_f16
        half2v p2 = __builtin_elementwise_max(pe, pf);       // v_pk_max_f16
        P.h2[kk] = p2;
        den[t] = __builtin_amdgcn_fdot2(p2, ones, den[t], false);
      }
      acc[t][0] = __builtin_amdgcn_mfma_f32_16x16x32_f16(P.h8, B0, acc[t][0], 0, 0, 0);
      acc[t][1] = __builtin_amdgcn_mfma_f32_16x16x32_f16(P.h8, B1, acc[t][1], 0, 0, 0);
    }
  }

  // ---- epilogue: cross-wave reduce + divide + elu + store ----
#pragma unroll
  for (int t = 0; t < 4; ++t) {
    den[t] += __shfl_xor(den[t], 16);
    den[t] += __shfl_xor(den[t], 32);
  }
  __syncthreads();                           // E/F dead; reuse smem
  float* redN = smem;                        // [4][64][33]
  float* redD = smem + 4 * 64 * 33;          // [4][64]
#pragma unroll
  for (int t = 0; t < 4; ++t) {
#pragma unroll
    for (int dh = 0; dh < 2; ++dh)
#pragma unroll
      for (int r = 0; r < 4; ++r)
        redN[(w * 64 + t * 16 + q * 4 + r) * 33 + dh * 16 + m] = acc[t][dh][r];
    if (q == 0) redD[w * 64 + t * 16 + m] = den[t];
  }
  __syncthreads();
  {
    int rl = tid >> 2, dg = (tid & 3) * 8;
    float num[8];
#pragma unroll
    for (int i = 0; i < 8; ++i)
      num[i] = redN[(0 * 64 + rl) * 33 + dg + i] + redN[(1 * 64 + rl) * 33 + dg + i] +
               redN[(2 * 64 + rl) * 33 + dg + i] + redN[(3 * 64 + rl) * 33 + dg + i];
    float dt = redD[rl] + redD[64 + rl] + redD[128 + rl] + redD[192 + rl];
    float rd = 1.0f / dt;                    // den >= ~1 by construction
    float* orow = out + (size_t)(b * Nn + tile * 64 + rl) * (4 * Dd) + h * Dd + dg;
#pragma unroll
    for (int i = 0; i < 8; ++i) {
      float hv = num[i] * rd;
      num[i] = hv > 0.f ? hv : (__builtin_amdgcn_exp2f(hv * LOG2E) - 1.0f);
    }
    *(float4*)orow = make_float4(num[0], num[1], num[2], num[3]);
    *((float4*)orow + 1) = make_float4(num[4], num[5], num[6], num[7]);
  }
}

extern "C" void kernel_launch(void* const* d_in, const int* in_sizes, int n_in,
                              void* d_out, int out_size, void* d_ws, size_t ws_size,
                              hipStream_t stream) {
  const float* x = (const float*)d_in[0];   // (4,2048,128)
  const float* W = (const float*)d_in[1];   // (4,128,32)
  const float* a = (const float*)d_in[2];   // (4,64)
  float* out = (float*)d_out;               // (4,2048,128)

  float* wsf = (float*)d_ws;
  float* sArr = wsf;                        // 32768 f32
  float* tArr = sArr + 32768;               // 32768 f32
  _Float16* whT = (_Float16*)(tArr + 32768);  // 16*32*2048 f16 = 2 MB

  k1_wh<<<dim3(512), dim3(256), 0, stream>>>(x, W, a, whT, sArr, tArr);
  k3_attn<<<dim3(512), dim3(256), 0, stream>>>(whT, sArr, tArr, out);
}